// Round 1
// baseline (250.034 us; speedup 1.0000x reference)
//
#include <hip/hip_runtime.h>
#include <cmath>

// EmbedMaskPostProcessor: top-k select + box decode + embedding-distance masks.
// Output [2,200,384,384] f32 = 236 MB, <1% nonzero -> write-BW bound (~37us floor).

namespace {
constexpr int NIMG = 2;
constexpr int NC   = 80;
constexpr int NHW  = 96 * 96;        // 9216
constexpr int NCHW = NC * NHW;       // 737280
constexpr int NDIM = 32;
constexpr int PH = 192, PW = 192;    // pixel_embed spatial
constexpr int OH = 384, OW = 384;    // output mask spatial
constexpr int KTOP = 200;
constexpr float PRE_THRESH = 0.05f;
constexpr unsigned KEY_ZERO = 0x80000000u;  // key of +0.0f; key > this <=> value > 0
constexpr float IMG_MAX = 767.0f;

// ws layout (4-byte words)
constexpr int WS_HIST1 = 0;                         // [NIMG][2048]
constexpr int WS_HIST2 = WS_HIST1 + NIMG * 2048;    // [NIMG][2048]
constexpr int WS_HIST3 = WS_HIST2 + NIMG * 2048;    // [NIMG][1024]
constexpr int WS_CNTA  = WS_HIST3 + NIMG * 1024;    // [NIMG]
constexpr int WS_CNTB  = WS_CNTA + NIMG;            // [NIMG]
constexpr int WS_BUFA  = WS_CNTB + NIMG;            // [NIMG][256][2] {key, refidx}
constexpr int WS_BUFB  = WS_BUFA + NIMG * 256 * 2;  // [NIMG][1024] refidx (ties)
constexpr int WS_PARAMS= WS_BUFB + NIMG * 1024;     // [NIMG][KTOP][40]
constexpr int WS_ZERO_END = WS_BUFA;                // zero hists + counters each call
constexpr int PARAM_WORDS = 40;  // [0]=valid [1..4]=ix0,ix1,iy0,iy1 [5]=margin [8..39]=e
}

__device__ __forceinline__ unsigned key_of(float f) {
  unsigned u = __float_as_uint(f);
  return (u & 0x80000000u) ? ~u : (u | 0x80000000u);  // monotone: bigger float -> bigger key
}

// score of candidate i (flat c*NHW+hw, native box_cls layout), recomputed per pass.
__device__ __forceinline__ unsigned key_at(const float* __restrict__ cls_n,
                                           const float* __restrict__ ctr_n, int i) {
  const float x = cls_n[i];
  const float s = 1.0f / (1.0f + expf(-x));
  float v = -1.0f;
  if (s > PRE_THRESH) {
    const float cv = ctr_n[i % NHW];
    const float c = 1.0f / (1.0f + expf(-cv));
    v = s * c;
  }
  return key_of(v);
}

// Find b* = max bucket with suffix-count >= krem_in; krem_out = krem_in - count(buckets > b*).
// Must be called by all 256 threads of the block.
__device__ void scan_select(const unsigned* __restrict__ gh, int nb, int krem_in,
                            int& b_out, int& krem_out) {
  __shared__ unsigned s_cnt[2048];
  __shared__ unsigned s_csum[256];
  __shared__ int s_b, s_k;
  const int t = threadIdx.x;
  __syncthreads();  // protect static shared reuse across calls
  if (t == 0) { s_b = -1; s_k = krem_in; }
  const int per = nb >> 8;
  unsigned local = 0;
  for (int j = 0; j < per; ++j) { unsigned v = gh[t * per + j]; s_cnt[t * per + j] = v; local += v; }
  s_csum[t] = local;
  __syncthreads();
  unsigned S = 0;  // suffix over higher thread-chunks
  for (int j = t + 1; j < 256; ++j) S += s_csum[j];
  int cand_b = -1;
  unsigned cand_above = 0;
  unsigned run = S;
  for (int j = per - 1; j >= 0; --j) {
    const unsigned cv = s_cnt[t * per + j];
    if (cand_b < 0 && run + cv >= (unsigned)krem_in) { cand_b = t * per + j; cand_above = run; }
    run += cv;
  }
  if (cand_b >= 0) atomicMax(&s_b, cand_b);
  __syncthreads();
  if (cand_b >= 0 && cand_b == s_b) s_k = krem_in - (int)cand_above;
  __syncthreads();
  b_out = (s_b < 0) ? 0 : s_b;
  krem_out = s_k;
}

__global__ __launch_bounds__(256) void k_zero_ws(unsigned* __restrict__ ws) {
  for (int i = blockIdx.x * 256 + threadIdx.x; i < WS_ZERO_END; i += gridDim.x * 256)
    ws[i] = 0u;
}

__global__ __launch_bounds__(256) void k_hist1(const float* __restrict__ box_cls,
                                               const float* __restrict__ ctrness,
                                               unsigned* __restrict__ ws) {
  const int n = blockIdx.y;
  __shared__ unsigned hist[2048];
  for (int i = threadIdx.x; i < 2048; i += 256) hist[i] = 0;
  __syncthreads();
  const float* cls = box_cls + n * NCHW;
  const float* ctr = ctrness + n * NHW;
  for (int i = blockIdx.x * 256 + threadIdx.x; i < NCHW; i += gridDim.x * 256) {
    const unsigned k = key_at(cls, ctr, i);
    atomicAdd(&hist[k >> 21], 1u);
  }
  __syncthreads();
  unsigned* gh = ws + WS_HIST1 + n * 2048;
  for (int i = threadIdx.x; i < 2048; i += 256) { unsigned v = hist[i]; if (v) atomicAdd(&gh[i], v); }
}

__global__ __launch_bounds__(256) void k_hist2(const float* __restrict__ box_cls,
                                               const float* __restrict__ ctrness,
                                               unsigned* __restrict__ ws) {
  const int n = blockIdx.y;
  int b1, k1;
  scan_select(ws + WS_HIST1 + n * 2048, 2048, KTOP, b1, k1);
  __shared__ unsigned hist[2048];
  for (int i = threadIdx.x; i < 2048; i += 256) hist[i] = 0;
  __syncthreads();
  const float* cls = box_cls + n * NCHW;
  const float* ctr = ctrness + n * NHW;
  const unsigned p1 = (unsigned)b1;
  for (int i = blockIdx.x * 256 + threadIdx.x; i < NCHW; i += gridDim.x * 256) {
    const unsigned k = key_at(cls, ctr, i);
    if ((k >> 21) == p1) atomicAdd(&hist[(k >> 10) & 2047u], 1u);
  }
  __syncthreads();
  unsigned* gh = ws + WS_HIST2 + n * 2048;
  for (int i = threadIdx.x; i < 2048; i += 256) { unsigned v = hist[i]; if (v) atomicAdd(&gh[i], v); }
}

__global__ __launch_bounds__(256) void k_hist3(const float* __restrict__ box_cls,
                                               const float* __restrict__ ctrness,
                                               unsigned* __restrict__ ws) {
  const int n = blockIdx.y;
  int b1, k1, b2, k2;
  scan_select(ws + WS_HIST1 + n * 2048, 2048, KTOP, b1, k1);
  scan_select(ws + WS_HIST2 + n * 2048, 2048, k1, b2, k2);
  __shared__ unsigned hist[1024];
  for (int i = threadIdx.x; i < 1024; i += 256) hist[i] = 0;
  __syncthreads();
  const float* cls = box_cls + n * NCHW;
  const float* ctr = ctrness + n * NHW;
  const unsigned p22 = ((unsigned)b1 << 11) | (unsigned)b2;
  for (int i = blockIdx.x * 256 + threadIdx.x; i < NCHW; i += gridDim.x * 256) {
    const unsigned k = key_at(cls, ctr, i);
    if ((k >> 10) == p22) atomicAdd(&hist[k & 1023u], 1u);
  }
  __syncthreads();
  unsigned* gh = ws + WS_HIST3 + n * 1024;
  for (int i = threadIdx.x; i < 1024; i += 256) { unsigned v = hist[i]; if (v) atomicAdd(&gh[i], v); }
}

__global__ __launch_bounds__(256) void k_gather(const float* __restrict__ box_cls,
                                                const float* __restrict__ ctrness,
                                                unsigned* __restrict__ ws) {
  const int n = blockIdx.y;
  int b1, k1, b2, k2, b3, k3;
  scan_select(ws + WS_HIST1 + n * 2048, 2048, KTOP, b1, k1);
  scan_select(ws + WS_HIST2 + n * 2048, 2048, k1, b2, k2);
  scan_select(ws + WS_HIST3 + n * 1024, 1024, k2, b3, k3);
  const unsigned thresh = ((unsigned)b1 << 21) | ((unsigned)b2 << 10) | (unsigned)b3;
  const float* cls = box_cls + n * NCHW;
  const float* ctr = ctrness + n * NHW;
  for (int i = blockIdx.x * 256 + threadIdx.x; i < NCHW; i += gridDim.x * 256) {
    const unsigned k = key_at(cls, ctr, i);
    if (k < thresh) continue;
    const int c = i / NHW;
    const int hw = i - c * NHW;
    const unsigned ref = (unsigned)(hw * NC + c);  // reference flat index (tie-break order)
    if (k > thresh) {
      const unsigned pos = atomicAdd(ws + WS_CNTA + n, 1u);
      if (pos < 256u) {
        ws[WS_BUFA + (n * 256 + (int)pos) * 2] = k;
        ws[WS_BUFA + (n * 256 + (int)pos) * 2 + 1] = ref;
      }
    } else {
      const unsigned pos = atomicAdd(ws + WS_CNTB + n, 1u);
      if (pos < 1024u) ws[WS_BUFB + n * 1024 + (int)pos] = ref;
    }
  }
}

__global__ __launch_bounds__(256) void k_final(unsigned* __restrict__ ws,
                                               const float* __restrict__ locations,
                                               const float* __restrict__ box_reg,
                                               const float* __restrict__ pemb,
                                               const float* __restrict__ pmar) {
  const int n = blockIdx.x;
  const int t = threadIdx.x;
  int b1, k1, b2, k2, b3, k3;
  scan_select(ws + WS_HIST1 + n * 2048, 2048, KTOP, b1, k1);
  scan_select(ws + WS_HIST2 + n * 2048, 2048, k1, b2, k2);
  scan_select(ws + WS_HIST3 + n * 1024, 1024, k2, b3, k3);
  const unsigned thresh = ((unsigned)b1 << 21) | ((unsigned)b2 << 10) | (unsigned)b3;
  const int krem = k3;
  __shared__ unsigned aKey[256], aRef[256];
  __shared__ int slotRef[256];
  __shared__ unsigned slotKey[256];
  __shared__ unsigned sB[1024];
  const int cntA = min((int)ws[WS_CNTA + n], 256);
  const int cntB = min((int)ws[WS_CNTB + n], 1024);
  if (t < cntA) {
    aKey[t] = ws[WS_BUFA + (n * 256 + t) * 2];
    aRef[t] = ws[WS_BUFA + (n * 256 + t) * 2 + 1];
  }
  slotRef[t] = -1;
  slotKey[t] = 0u;
  for (int i = t; i < cntB; i += 256) sB[i] = ws[WS_BUFB + n * 1024 + i];
  __syncthreads();
  if (t < cntA) {  // exact rank: value desc, index asc (matches lax.top_k)
    const unsigned mk = aKey[t], mr = aRef[t];
    int rank = 0;
    for (int j = 0; j < cntA; ++j) {
      const unsigned kj = aKey[j], rj = aRef[j];
      rank += (kj > mk || (kj == mk && rj < mr)) ? 1 : 0;
    }
    slotRef[rank] = (int)mr;
    slotKey[rank] = mk;
  }
  const bool tieValid = thresh > KEY_ZERO;  // tie value > 0 -> slot contributes
  int take = min(min(krem, cntB), KTOP - cntA);
  if (take < 0) take = 0;
  if (tieValid) {
    for (int i = t; i < cntB; i += 256) {
      const unsigned mr = sB[i];
      int r = 0;
      for (int j = 0; j < cntB; ++j) r += (sB[j] < mr) ? 1 : 0;
      if (r < take) { slotRef[cntA + r] = (int)mr; slotKey[cntA + r] = thresh; }
    }
  }
  __syncthreads();
  if (t < KTOP) {
    const int ref = slotRef[t];
    const unsigned key = slotKey[t];
    unsigned* pp = ws + WS_PARAMS + (n * KTOP + t) * PARAM_WORDS;
    int valid = 0;
    if (ref >= 0 && key > KEY_ZERO) {
      const int hw = ref / NC;
      const float lx = locations[2 * hw], ly = locations[2 * hw + 1];
      const float rl = box_reg[(n * 4 + 0) * NHW + hw];
      const float rt = box_reg[(n * 4 + 1) * NHW + hw];
      const float rr = box_reg[(n * 4 + 2) * NHW + hw];
      const float rb = box_reg[(n * 4 + 3) * NHW + hw];
      const float x1 = fminf(fmaxf(lx - rl, 0.f), IMG_MAX);
      const float y1 = fminf(fmaxf(ly - rt, 0.f), IMG_MAX);
      const float x2 = fminf(fmaxf(lx + rr, 0.f), IMG_MAX);
      const float y2 = fminf(fmaxf(ly + rb, 0.f), IMG_MAX);
      // mask coords = box/4; inclusive integer bounds (xs >= x1m && xs <= x2m)
      const int ix0 = max(0, (int)ceilf(x1 * 0.25f));
      const int ix1 = min(OW - 1, (int)floorf(x2 * 0.25f));
      const int iy0 = max(0, (int)ceilf(y1 * 0.25f));
      const int iy1 = min(OH - 1, (int)floorf(y2 * 0.25f));
      if (ix0 <= ix1 && iy0 <= iy1) {
        valid = 1;
        pp[1] = (unsigned)ix0; pp[2] = (unsigned)ix1;
        pp[3] = (unsigned)iy0; pp[4] = (unsigned)iy1;
        reinterpret_cast<float*>(pp)[5] = pmar[n * NHW + hw];
        float* ep = reinterpret_cast<float*>(pp) + 8;
        #pragma unroll
        for (int d = 0; d < NDIM; ++d) ep[d] = pemb[(n * NDIM + d) * NHW + hw];
      }
    }
    pp[0] = (unsigned)valid;
  }
}

// Fused zero-fill + in-box mask compute. Tile = 16 rows x 384 cols per (n,k).
__global__ __launch_bounds__(256) void k_mask(const float* __restrict__ pix,
                                              const unsigned* __restrict__ ws,
                                              float* __restrict__ out) {
  const int nk = blockIdx.x;          // n*KTOP + k
  const int r0 = blockIdx.y * 16;
  float* ob = out + (size_t)nk * (OH * OW);
  const unsigned* meta = ws + WS_PARAMS + nk * PARAM_WORDS;
  const int valid = (int)meta[0];
  int ix0 = 0, ix1 = -1, iy0 = 0, iy1 = -1;
  float margin = 0.0f;
  if (valid) {
    ix0 = (int)meta[1]; ix1 = (int)meta[2];
    iy0 = (int)meta[3]; iy1 = (int)meta[4];
    margin = __uint_as_float(meta[5]);
  }
  const bool overlap = valid && (iy1 >= r0) && (iy0 <= r0 + 15);
  constexpr int F4 = 16 * OW / 4;     // 1536 float4 per tile
  if (!overlap) {                     // fast path: pure zero store (99% of tiles)
    const float4 z = make_float4(0.f, 0.f, 0.f, 0.f);
    float4* o4 = reinterpret_cast<float4*>(ob + (size_t)r0 * OW);
    for (int f = threadIdx.x; f < F4; f += 256) o4[f] = z;
    return;
  }
  float e[NDIM];
  const float4* e4 = reinterpret_cast<const float4*>(meta + 8);
  #pragma unroll
  for (int q = 0; q < NDIM / 4; ++q) {
    const float4 v = e4[q];
    e[4 * q + 0] = v.x; e[4 * q + 1] = v.y; e[4 * q + 2] = v.z; e[4 * q + 3] = v.w;
  }
  const int n = nk / KTOP;
  const float* peb = pix + (size_t)n * NDIM * PH * PW;
  for (int f = threadIdx.x; f < F4; f += 256) {
    const int row = f / (OW / 4);
    const int xq = f - row * (OW / 4);
    const int y = r0 + row;
    const int x0 = xq * 4;
    float rp[4] = {0.f, 0.f, 0.f, 0.f};
    if (y >= iy0 && y <= iy1 && x0 + 3 >= ix0 && x0 <= ix1) {
      // on-the-fly 2x bilinear (align_corners=False): src = 0.5*dst - 0.25, edge-clamped
      const float sy = 0.5f * (float)y - 0.25f;
      const float yf = floorf(sy);
      const float fy = sy - yf;
      int ys0 = (int)yf, ys1 = ys0 + 1;
      ys0 = max(ys0, 0); ys1 = min(ys1, PH - 1);
      #pragma unroll
      for (int xi = 0; xi < 4; ++xi) {
        const int x = x0 + xi;
        if (x < ix0 || x > ix1) continue;
        const float sx = 0.5f * (float)x - 0.25f;
        const float xf = floorf(sx);
        const float fx = sx - xf;
        int xs0 = (int)xf, xs1 = xs0 + 1;
        xs0 = max(xs0, 0); xs1 = min(xs1, PW - 1);
        const float w00 = (1.f - fy) * (1.f - fx);
        const float w01 = (1.f - fy) * fx;
        const float w10 = fy * (1.f - fx);
        const float w11 = fy * fx;
        const int o00 = ys0 * PW + xs0, o01 = ys0 * PW + xs1;
        const int o10 = ys1 * PW + xs0, o11 = ys1 * PW + xs1;
        float d2 = 0.f;
        const float* pd = peb;
        #pragma unroll
        for (int d = 0; d < NDIM; ++d) {
          const float p = w00 * pd[o00] + w01 * pd[o01] + w10 * pd[o10] + w11 * pd[o11];
          const float df = e[d] - p;
          d2 = fmaf(df, df, d2);
          pd += PH * PW;
        }
        rp[xi] = expf(-d2 * margin);
      }
    }
    const float4 res = make_float4(rp[0], rp[1], rp[2], rp[3]);
    *reinterpret_cast<float4*>(ob + (size_t)y * OW + x0) = res;
  }
}

extern "C" void kernel_launch(void* const* d_in, const int* in_sizes, int n_in,
                              void* d_out, int out_size, void* d_ws, size_t ws_size,
                              hipStream_t stream) {
  const float* locations = (const float*)d_in[0];
  const float* box_cls   = (const float*)d_in[1];
  const float* box_reg   = (const float*)d_in[2];
  const float* ctrness   = (const float*)d_in[3];
  const float* pemb      = (const float*)d_in[4];
  const float* pmar      = (const float*)d_in[5];
  const float* pix       = (const float*)d_in[6];
  float* out = (float*)d_out;
  unsigned* ws = (unsigned*)d_ws;
  // ws need: (WS_PARAMS + NIMG*KTOP*40)*4 = ~118 KB  (<< ws_size)

  k_zero_ws<<<dim3(40), dim3(256), 0, stream>>>(ws);
  k_hist1 <<<dim3(128, NIMG), dim3(256), 0, stream>>>(box_cls, ctrness, ws);
  k_hist2 <<<dim3(128, NIMG), dim3(256), 0, stream>>>(box_cls, ctrness, ws);
  k_hist3 <<<dim3(128, NIMG), dim3(256), 0, stream>>>(box_cls, ctrness, ws);
  k_gather<<<dim3(128, NIMG), dim3(256), 0, stream>>>(box_cls, ctrness, ws);
  k_final <<<dim3(NIMG), dim3(256), 0, stream>>>(ws, locations, box_reg, pemb, pmar);
  k_mask  <<<dim3(NIMG * KTOP, OH / 16), dim3(256), 0, stream>>>(pix, ws, out);
}